// Round 1
// baseline (91.501 us; speedup 1.0000x reference)
//
#include <hip/hip_runtime.h>

#define BB 2
#define KK 16
#define WW 128
#define HH 128
#define NPIX (WW*HH)   // 16384

// ws layout:
//   bytes [0 .. 127]  : uint32 maxD2[32] (b*16+k), float acc (at offset 128-... we use offset 32*4=128? no:)
//   [0..127]: 32 x uint32 maxD2  (128 bytes)
//   [128..131]: float loss accumulator
//   [256 ...]: int32 D2[B*K*NPIX]  (2 MB)

__global__ __launch_bounds__(256) void edt_kernel(const int* __restrict__ mask,
                                                  unsigned int* __restrict__ maxD2,
                                                  int* __restrict__ d2out) {
    __shared__ unsigned char nuc[NPIX];      // 16 KB
    __shared__ unsigned short ndsq[NPIX];    // 32 KB (nearest-dist, then squared)
    const int rg = blockIdx.x;   // 0..7  (16-row group)
    const int k  = blockIdx.y;   // 0..15
    const int b  = blockIdx.z;   // 0..1
    const int t  = threadIdx.x;
    const int label = k + 1;
    const int* mb = mask + b * NPIX;

    for (int idx = t; idx < NPIX; idx += 256)
        nuc[idx] = (mb[idx] == label) ? 1 : 0;
    __syncthreads();

    // 1D nearest-background distance per column (exact), sentinel 200 if no bg
    if (t < 128) {
        const int j = t;
        int dist = 200;
        for (int i = 0; i < 128; ++i) {
            dist = nuc[i*128 + j] ? ((dist < 200) ? dist + 1 : 200) : 0;
            ndsq[i*128 + j] = (unsigned short)dist;   // temp: downward dist
        }
        dist = 200;
        for (int i = 127; i >= 0; --i) {
            dist = nuc[i*128 + j] ? ((dist < 200) ? dist + 1 : 200) : 0;
            int nd = min(dist, (int)ndsq[i*128 + j]);
            ndsq[i*128 + j] = (unsigned short)(nd * nd);  // G2 (<= 40000)
        }
    }
    __syncthreads();

    // Row pass: D2[i][j] = min_j' ndsq[i][j'] + (j-j')^2  (exact integer)
    const int row = rg * 16 + (t >> 4);
    const int jo  = t & 15;
    const unsigned short* grow = &ndsq[row * 128];
    int best[8];
#pragma unroll
    for (int u = 0; u < 8; ++u) best[u] = 0x7fffffff;
    for (int jp = 0; jp < 128; ++jp) {
        const int g = (int)grow[jp];
#pragma unroll
        for (int u = 0; u < 8; ++u) {
            int dj = (jo + 16*u) - jp;
            int cand = g + dj * dj;
            best[u] = min(best[u], cand);
        }
    }
    int* drow = d2out + ((b * KK + k) * NPIX) + row * 128;
    int bm = 0;
#pragma unroll
    for (int u = 0; u < 8; ++u) {
        drow[jo + 16*u] = best[u];
        bm = max(bm, best[u]);
    }
    // block max -> atomicMax (deterministic, integer)
    for (int off = 32; off; off >>= 1)
        bm = max(bm, __shfl_down(bm, off, 64));
    __shared__ int wmax[4];
    if ((t & 63) == 0) wmax[t >> 6] = bm;
    __syncthreads();
    if (t == 0) {
        int m = max(max(wmax[0], wmax[1]), max(wmax[2], wmax[3]));
        atomicMax(&maxD2[b * KK + k], (unsigned int)m);
    }
}

__global__ __launch_bounds__(256) void gt_loss_kernel(const float* __restrict__ pred,
                                                      const float* __restrict__ ign,
                                                      const int* __restrict__ d2,
                                                      const unsigned int* __restrict__ maxD2,
                                                      float* __restrict__ out,
                                                      float* __restrict__ acc) {
    const int p  = blockIdx.x * 256 + threadIdx.x;  // 0..32767 (b,w,h)
    const int b  = p >> 14;
    const int pp = p & (NPIX - 1);

    float gt[8];
#pragma unroll
    for (int c = 0; c < 8; ++c) gt[c] = 0.0f;
    const float ddd[8] = {0.83f, 0.68f, 0.54f, 0.41f, 0.29f, 0.18f, 0.09f, 0.0f};

    for (int k = 0; k < KK; ++k) {
        int D2 = d2[(b * KK + k) * NPIX + pp];
        if (D2 >= 1) {                     // nuclei pixel for this k
            float d  = __fsqrt_rn((float)D2);
            float m  = __fsqrt_rn((float)maxD2[b * KK + k]);  // >0 since D2>=1
            float dn = __fdiv_rn(d, m);
            if (dn < 0.5f) dn = 0.0f;
            if (dn > 0.7f) dn = 1.0f;
#pragma unroll
            for (int c = 0; c < 8; ++c) {
                if (dn >= ddd[c]) { gt[c] += 1.0f; break; }
            }
        }
    }

    float lsum = 0.0f;
#pragma unroll
    for (int c = 0; c < 8; ++c) {
        const float g = gt[c];
        out[1 + ((b * 8 + c) * NPIX) + pp] = g;
        float diff = pred[(b * 8 + c) * NPIX + pp] - g;
        float ad = fabsf(diff);
        lsum += (ad < 1.0f) ? 0.5f * diff * diff : (ad - 0.5f);
    }
    float contrib = lsum * 0.125f * ign[p];

    for (int off = 32; off; off >>= 1)
        contrib += __shfl_down(contrib, off, 64);
    __shared__ float wsum[4];
    if ((threadIdx.x & 63) == 0) wsum[threadIdx.x >> 6] = contrib;
    __syncthreads();
    if (threadIdx.x == 0)
        atomicAdd(acc, wsum[0] + wsum[1] + wsum[2] + wsum[3]);
}

__global__ void finalize_kernel(const float* __restrict__ acc, float* __restrict__ out) {
    if (threadIdx.x == 0) out[0] = acc[0] * (1.0f / 32768.0f);
}

extern "C" void kernel_launch(void* const* d_in, const int* in_sizes, int n_in,
                              void* d_out, int out_size, void* d_ws, size_t ws_size,
                              hipStream_t stream) {
    const float* pred = (const float*)d_in[0];
    const int*   mask = (const int*)d_in[1];
    const float* ign  = (const float*)d_in[2];
    float* out = (float*)d_out;

    unsigned int* maxD2 = (unsigned int*)d_ws;                 // 32 u32
    float*        acc   = (float*)((char*)d_ws + 128);         // 1 f32
    int*          d2    = (int*)((char*)d_ws + 256);           // 2 MB

    hipMemsetAsync(d_ws, 0, 256, stream);  // zero maxD2 + acc (ws is poisoned)

    edt_kernel<<<dim3(8, 16, 2), 256, 0, stream>>>(mask, maxD2, d2);
    gt_loss_kernel<<<(BB * NPIX) / 256, 256, 0, stream>>>(pred, ign, d2, maxD2, out, acc);
    finalize_kernel<<<1, 64, 0, stream>>>(acc, out);
}